// Round 5
// baseline (1266.034 us; speedup 1.0000x reference)
//
#include <hip/hip_runtime.h>
#include <stdint.h>
#include <type_traits>

// Problem constants
#define BB  4
#define SS  2048
#define DD  1024
#define HH  16
#define HDD 64

typedef __attribute__((ext_vector_type(8)))  short s16x8;   // 8 bf16 (4 VGPRs)
typedef __attribute__((ext_vector_type(4)))  float f32x4;   // MFMA C/D 16x16
typedef __attribute__((ext_vector_type(16))) float f32x16;  // MFMA C/D 32x32

__device__ inline short f2bf(float f) {
    union { float f; unsigned int u; } v; v.f = f;
    unsigned int r = (v.u + 0x7fffu + ((v.u >> 16) & 1u)) >> 16; // RNE
    return (short)r;
}
// pack two f32 -> bf16x2 with +0x8000 round (1 v_perm + 2 v_add)
__device__ inline unsigned int permpack(float a, float b) {
    union { float f; unsigned int u; } x, y; x.f = a; y.f = b;
    return __builtin_amdgcn_perm(y.u + 0x8000u, x.u + 0x8000u, 0x07060302u);
}

#define GLL(gp, lp) __builtin_amdgcn_global_load_lds( \
    (const __attribute__((address_space(1))) void*)(gp), \
    (__attribute__((address_space(3))) void*)(lp), 16, 0, 0)

// ---------------- fp32 -> bf16 cast (n % 8 == 0) ----------------
__global__ void cvt_kernel(const float* __restrict__ src, short* __restrict__ dst, int n) {
    int i = (blockIdx.x * 256 + threadIdx.x) * 8;
    if (i >= n) return;
    const float4* s = (const float4*)(src + i);
    float4 a = s[0], b = s[1];
    s16x8 o;
    o[0]=f2bf(a.x); o[1]=f2bf(a.y); o[2]=f2bf(a.z); o[3]=f2bf(a.w);
    o[4]=f2bf(b.x); o[5]=f2bf(b.y); o[6]=f2bf(b.z); o[7]=f2bf(b.w);
    *(s16x8*)(dst + i) = o;
}

// ---------------- GEMM C = A @ B^T + bias (m97 structure) ----------------
// EPI=1: QKV scatter; Q is PRE-SCALED by (1/8)*log2(e) for the attention softmax.
template<int EPI>
__global__ __launch_bounds__(256)
void gemm_bt(const short* __restrict__ A, const short* __restrict__ Bw,
             const float* __restrict__ bias, float* __restrict__ Cf,
             short* __restrict__ Qo, short* __restrict__ Ko, short* __restrict__ Vo,
             int M, int N, int K)
{
    __shared__ short lsA[128 * 32];
    __shared__ short lsB[128 * 32];
    const int tid  = threadIdx.x;
    const int w    = tid >> 6, lane = tid & 63;
    const int quad = lane >> 4, l15 = lane & 15;
    const int m0 = blockIdx.x * 128, n0 = blockIdx.y * 128;
    const int mw = (w & 1) * 64, nw = (w >> 1) * 64;

    f32x4 acc[4][4] = {};

    const int srow = w * 32 + (lane >> 2);
    const int scol = (lane & 3) * 8;
    const short* pA = A + (size_t)(m0 + srow) * K + scol;
    const short* pB = Bw + (size_t)(n0 + srow) * K + scol;
    short* lAbase0 = &lsA[(w * 32) * 32];
    short* lAbase1 = &lsA[(w * 32 + 16) * 32];
    short* lBbase0 = &lsB[(w * 32) * 32];
    short* lBbase1 = &lsB[(w * 32 + 16) * 32];

    for (int kk = 0; kk < K; kk += 32) {
        __syncthreads();
        GLL(pA + kk,            lAbase0);
        GLL(pA + kk + 16 * K,   lAbase1);
        GLL(pB + kk,            lBbase0);
        GLL(pB + kk + 16 * K,   lBbase1);
        asm volatile("s_waitcnt vmcnt(0)" ::: "memory");
        __syncthreads();

        s16x8 af[4], bfr[4];
        for (int t = 0; t < 4; ++t) {
            af[t]  = *(const s16x8*)&lsA[(mw + t * 16 + l15) * 32 + quad * 8];
            bfr[t] = *(const s16x8*)&lsB[(nw + t * 16 + l15) * 32 + quad * 8];
        }
        for (int i = 0; i < 4; ++i)
            for (int j = 0; j < 4; ++j)
                acc[i][j] = __builtin_amdgcn_mfma_f32_16x16x32_bf16(af[i], bfr[j], acc[i][j], 0, 0, 0);
    }

    if (EPI == 0) {
        for (int i = 0; i < 4; ++i) {
            int row = m0 + mw + i * 16 + quad * 4;
            for (int j = 0; j < 4; ++j) {
                int col = n0 + nw + j * 16 + l15;
                float bv = bias[col];
                for (int r = 0; r < 4; ++r)
                    Cf[(size_t)(row + r) * N + col] = acc[i][j][r] + bv;
            }
        }
    } else {
        const float QSC = 0.18033688f;   // (1/8)*log2(e) folded into Q
        for (int i = 0; i < 4; ++i) {
            int row = m0 + mw + i * 16 + quad * 4;
            for (int j = 0; j < 4; ++j) {
                int col = n0 + nw + j * 16 + l15;
                float bv = bias[col];
                int sel = col >> 10, h = (col >> 6) & 15, hd = col & 63;
                for (int r = 0; r < 4; ++r) {
                    int rr = row + r;
                    int b = rr >> 11, s = rr & 2047;
                    float av = acc[i][j][r] + bv;
                    if (sel == 0)      Qo[(((size_t)b * HH + h) * SS + s) * HDD + hd] = f2bf(av * QSC);
                    else if (sel == 1) Ko[(((size_t)b * HH + h) * SS + s) * HDD + hd] = f2bf(av);
                    else               Vo[(((size_t)b * HH + h) * HDD + hd) * SS + s] = f2bf(av);
                }
            }
        }
    }
}

// ---------------- causal flash attention, 32x32 MFMA, S^T form, pipelined ----------------
// Q(pre-scaled),K: (b,h,s,hd) bf16; V: (b,h,hd,s) bf16; O: (b,s,h*64+hd) bf16.
// grid (16, B*H), 1024 blocks (4/CU). Block = one 128-q-row tile, qb interleaved
// for load balance. K/V/mask double-buffered in LDS; GLL for tile kt+1 issued
// BEFORE computing tile kt, so the barrier's vmcnt(0) drain is ~free.
__global__ __launch_bounds__(256, 4)
void attn_kernel(const short* __restrict__ Q, const short* __restrict__ Kb,
                 const short* __restrict__ Vb, const int* __restrict__ mask,
                 short* __restrict__ O)
{
    __shared__ short lsK[2][64 * 64];   // chunk p=key*8+(s^(key&7)) holds K[kv0+key][s'*8..]
    __shared__ short lsV[2][64 * 64];   // chunk p=hd*8+(s^(hd&7))  holds V^T[hd][kv0+s'*8..]
    __shared__ float lsM[2][64];        // additive key mask

    const int tid = threadIdx.x;
    const int w   = tid >> 6, lane = tid & 63;
    const int h   = lane >> 5, q = lane & 31;     // half-wave, q-column
    const int bx = blockIdx.x, bh = blockIdx.y;
    const int qb = (bx & 1) ? (15 - (bx >> 1)) : (bx >> 1);   // interleave heavy/light
    const int b = bh >> 4;
    const size_t baseQK = (size_t)bh * SS * HDD;
    const size_t baseV  = (size_t)bh * HDD * SS;
    const int q0 = qb * 128;
    const int s_row = q0 + w * 32 + q;
    const int T = 2 * (qb + 1);                   // 64-key tiles; last 2 causal

    // Q fragments (B-frag: n=q, k=hd=kb*16+h*8+j), pre-scaled
    s16x8 bq[4];
    for (int kb = 0; kb < 4; ++kb)
        bq[kb] = *(const s16x8*)(Q + baseQK + (size_t)s_row * HDD + kb * 16 + h * 8);

    // staging addresses: 2 GLL slots each for K and V
    const short* gK[2]; const short* gV[2]; int lofs[2];
    for (int i = 0; i < 2; ++i) {
        const int p = w * 128 + i * 64 + lane;
        const int kr = p >> 3, s = p & 7;
        gK[i] = Kb + baseQK + (size_t)kr * HDD + ((s ^ (kr & 7)) * 8);
        gV[i] = Vb + baseV + (size_t)kr * SS + ((s ^ (kr & 7)) * 8);
        lofs[i] = (w * 128 + i * 64) * 8;         // wave-uniform LDS chunk base (shorts)
    }
    const int* mbase = mask + b * SS;

    float lsum = 0.f;
    f32x16 oa[2] = {};                            // O^T accs (hd halves)

    // ---- preamble: stage tile 0 into buf 0 ----
    for (int i = 0; i < 2; ++i) {
        GLL(gK[i], &lsK[0][lofs[i]]);
        GLL(gV[i], &lsV[0][lofs[i]]);
    }
    if (tid < 16) {
        int4 mv = *(const int4*)(mbase + tid * 4);
        float4 f;
        f.x = mv.x ? 0.f : -1e30f; f.y = mv.y ? 0.f : -1e30f;
        f.z = mv.z ? 0.f : -1e30f; f.w = mv.w ? 0.f : -1e30f;
        *(float4*)&lsM[0][tid * 4] = f;
    }
    __syncthreads();

    auto step = [&](int kt, auto CC) {
        constexpr bool CAUS = decltype(CC)::value;
        const int cur = kt & 1, nxt = cur ^ 1;
        const int kv0 = kt * 64;

        // prefetch tile kt+1 into buf[nxt] (lands during this tile's compute)
        int4 mv;
        const bool pf = (kt + 1 < T);
        if (pf) {
            const size_t okK = (size_t)(kv0 + 64) * HDD;
            const int   okV = kv0 + 64;
            for (int i = 0; i < 2; ++i) {
                GLL(gK[i] + okK, &lsK[nxt][lofs[i]]);
                GLL(gV[i] + okV, &lsV[nxt][lofs[i]]);
            }
            if (tid < 16) mv = *(const int4*)(mbase + kv0 + 64 + tid * 4);
        }

        // ---- compute tile kt from buf[cur] ----
        for (int nt = 0; nt < 2; ++nt) {
            // S^T: rows = keys nt*32 + (reg&3)+8*(reg>>2)+4h, col = q
            f32x16 sa = {};
            const int key = nt * 32 + q;
            for (int kb = 0; kb < 4; ++kb) {
                const int cc = (kb * 2 + h) ^ (key & 7);
                s16x8 ak = *(const s16x8*)&lsK[cur][(key * 8 + cc) * 8];
                sa = __builtin_amdgcn_mfma_f32_32x32x16_bf16(ak, bq[kb], sa, 0, 0, 0);
            }
            // softmax (fixed-offset, log2 domain; Q pre-scaled)
            unsigned int pk2[4][2];
            for (int g = 0; g < 4; ++g) {
                float4 mq = *(const float4*)&lsM[cur][nt * 32 + 8 * g + 4 * h];
                float pv[4];
                for (int r = 0; r < 4; ++r) {
                    float v = sa[g * 4 + r] + ((const float*)&mq)[r];
                    if (CAUS) {
                        int keyg = kv0 + nt * 32 + 8 * g + 4 * h + r;
                        if (keyg > s_row) v = -1e30f;
                    }
                    float p = __builtin_amdgcn_exp2f(v);
                    pv[r] = p;
                    lsum += p;
                }
                pk2[g][0] = permpack(pv[0], pv[1]);
                pk2[g][1] = permpack(pv[2], pv[3]);
            }
            // O^T += V^T P^T : P B-frag via half-wave exchange
            for (int kb2 = 0; kb2 < 2; ++kb2) {
                const int g_own = 2 * kb2 + h;
                unsigned int s0 = h ? pk2[2 * kb2][0] : pk2[2 * kb2 + 1][0];
                unsigned int s1 = h ? pk2[2 * kb2][1] : pk2[2 * kb2 + 1][1];
                unsigned int r0 = (unsigned int)__shfl_xor((int)s0, 32);
                unsigned int r1 = (unsigned int)__shfl_xor((int)s1, 32);
                union { s16x8 v; unsigned int d[4]; } bp;
                if (h == 0) { bp.d[0] = pk2[g_own][0]; bp.d[1] = pk2[g_own][1]; bp.d[2] = r0; bp.d[3] = r1; }
                else        { bp.d[0] = r0; bp.d[1] = r1; bp.d[2] = pk2[g_own][0]; bp.d[3] = pk2[g_own][1]; }
                for (int mt = 0; mt < 2; ++mt) {
                    const int hd = mt * 32 + q;
                    const int cc = (nt * 4 + kb2 * 2 + h) ^ (hd & 7);
                    s16x8 av = *(const s16x8*)&lsV[cur][(hd * 8 + cc) * 8];
                    oa[mt] = __builtin_amdgcn_mfma_f32_32x32x16_bf16(av, bp.v, oa[mt], 0, 0, 0);
                }
            }
        }

        if (pf && tid < 16) {
            float4 f;
            f.x = mv.x ? 0.f : -1e30f; f.y = mv.y ? 0.f : -1e30f;
            f.z = mv.z ? 0.f : -1e30f; f.w = mv.w ? 0.f : -1e30f;
            *(float4*)&lsM[nxt][tid * 4] = f;
        }
        __syncthreads();   // vmcnt(0) drain ~free: GLLs issued a whole tile ago
    };

    int kt = 0;
    for (; kt < T - 2; ++kt) step(kt, std::false_type{});
    step(kt, std::true_type{}); ++kt;
    step(kt, std::true_type{});

    // epilogue: normalize, O^T regs -> O (b, s, head*64+hd) bf16
    float ls2 = lsum + __shfl_xor(lsum, 32);
    float inv = 1.0f / ls2;
    const int hcol = (bh & 15) * HDD;
    const size_t obase = ((size_t)b * SS + s_row) * DD + hcol;
    for (int mt = 0; mt < 2; ++mt) {
        for (int g = 0; g < 4; ++g) {
            const int hd0 = mt * 32 + 8 * g + 4 * h;
            uint2 st;
            st.x = permpack(oa[mt][g * 4 + 0] * inv, oa[mt][g * 4 + 1] * inv);
            st.y = permpack(oa[mt][g * 4 + 2] * inv, oa[mt][g * 4 + 3] * inv);
            *(uint2*)&O[obase + hd0] = st;
        }
    }
}

// ---------------- launch ----------------
extern "C" void kernel_launch(void* const* d_in, const int* in_sizes, int n_in,
                              void* d_out, int out_size, void* d_ws, size_t ws_size,
                              hipStream_t stream) {
    const float* x     = (const float*)d_in[0];
    const int*   mask  = (const int*)d_in[1];
    const float* qkv_w = (const float*)d_in[2];
    const float* qkv_b = (const float*)d_in[3];
    const float* out_w = (const float*)d_in[4];
    const float* out_b = (const float*)d_in[5];
    float* out = (float*)d_out;

    const size_t M1 = (size_t)BB * SS;       // 8192
    short* ws  = (short*)d_ws;
    short* xb  = ws;
    short* qwb = xb  + M1 * DD;
    short* owb = qwb + (size_t)3 * DD * DD;
    short* Qb  = owb + (size_t)DD * DD;
    short* Kb  = Qb  + M1 * DD;
    short* Vb  = Kb  + M1 * DD;
    short* Ob  = Vb  + M1 * DD;

    cvt_kernel<<<(int)(M1 * DD / 8 / 256), 256, 0, stream>>>(x, xb, (int)(M1 * DD));
    cvt_kernel<<<3 * DD * DD / 8 / 256, 256, 0, stream>>>(qkv_w, qwb, 3 * DD * DD);
    cvt_kernel<<<DD * DD / 8 / 256, 256, 0, stream>>>(out_w, owb, DD * DD);

    gemm_bt<1><<<dim3(64, 24), 256, 0, stream>>>(xb, qwb, qkv_b, nullptr,
                                                 Qb, Kb, Vb, 8192, 3072, 1024);
    attn_kernel<<<dim3(16, BB * HH), 256, 0, stream>>>(Qb, Kb, Vb, mask, Ob);
    gemm_bt<0><<<dim3(64, 8), 256, 0, stream>>>(Ob, owb, out_b, out,
                                                nullptr, nullptr, nullptr, 8192, 1024, 1024);
}

// Round 6
// 341.312 us; speedup vs baseline: 3.7093x; 3.7093x over previous
//
#include <hip/hip_runtime.h>
#include <stdint.h>
#include <type_traits>

// Problem constants
#define BB  4
#define SS  2048
#define DD  1024
#define HH  16
#define HDD 64

typedef __attribute__((ext_vector_type(8)))  short s16x8;   // 8 bf16 (4 VGPRs)
typedef __attribute__((ext_vector_type(4)))  float f32x4;   // MFMA C/D 16x16
typedef __attribute__((ext_vector_type(16))) float f32x16;  // MFMA C/D 32x32

__device__ inline short f2bf(float f) {
    union { float f; unsigned int u; } v; v.f = f;
    unsigned int r = (v.u + 0x7fffu + ((v.u >> 16) & 1u)) >> 16; // RNE
    return (short)r;
}
// pack two f32 -> bf16x2 with +0x8000 round (1 v_perm + 2 v_add)
__device__ inline unsigned int permpack(float a, float b) {
    union { float f; unsigned int u; } x, y; x.f = a; y.f = b;
    return __builtin_amdgcn_perm(y.u + 0x8000u, x.u + 0x8000u, 0x07060302u);
}

#define GLL(gp, lp) __builtin_amdgcn_global_load_lds( \
    (const __attribute__((address_space(1))) void*)(gp), \
    (__attribute__((address_space(3))) void*)(lp), 16, 0, 0)

// ---------------- fp32 -> bf16 cast (n % 8 == 0) ----------------
__global__ void cvt_kernel(const float* __restrict__ src, short* __restrict__ dst, int n) {
    int i = (blockIdx.x * 256 + threadIdx.x) * 8;
    if (i >= n) return;
    const float4* s = (const float4*)(src + i);
    float4 a = s[0], b = s[1];
    s16x8 o;
    o[0]=f2bf(a.x); o[1]=f2bf(a.y); o[2]=f2bf(a.z); o[3]=f2bf(a.w);
    o[4]=f2bf(b.x); o[5]=f2bf(b.y); o[6]=f2bf(b.z); o[7]=f2bf(b.w);
    *(s16x8*)(dst + i) = o;
}

// ---------------- GEMM C = A @ B^T + bias (m97 structure) ----------------
// NOTE: byte-identical to the R4 version (healthy for 3 rounds). The R5 QSC
// epilogue tweak correlated with a pathological compile (VGPR 32, 3.2 GB
// scratch writes, 1 ms) — reverted; softmax scale lives in attn as a v_fma.
template<int EPI>
__global__ __launch_bounds__(256)
void gemm_bt(const short* __restrict__ A, const short* __restrict__ Bw,
             const float* __restrict__ bias, float* __restrict__ Cf,
             short* __restrict__ Qo, short* __restrict__ Ko, short* __restrict__ Vo,
             int M, int N, int K)
{
    __shared__ short lsA[128 * 32];
    __shared__ short lsB[128 * 32];
    const int tid  = threadIdx.x;
    const int w    = tid >> 6, lane = tid & 63;
    const int quad = lane >> 4, l15 = lane & 15;
    const int m0 = blockIdx.x * 128, n0 = blockIdx.y * 128;
    const int mw = (w & 1) * 64, nw = (w >> 1) * 64;

    f32x4 acc[4][4] = {};

    const int srow = w * 32 + (lane >> 2);
    const int scol = (lane & 3) * 8;
    const short* pA = A + (size_t)(m0 + srow) * K + scol;
    const short* pB = Bw + (size_t)(n0 + srow) * K + scol;
    short* lAbase0 = &lsA[(w * 32) * 32];
    short* lAbase1 = &lsA[(w * 32 + 16) * 32];
    short* lBbase0 = &lsB[(w * 32) * 32];
    short* lBbase1 = &lsB[(w * 32 + 16) * 32];

    for (int kk = 0; kk < K; kk += 32) {
        __syncthreads();
        GLL(pA + kk,            lAbase0);
        GLL(pA + kk + 16 * K,   lAbase1);
        GLL(pB + kk,            lBbase0);
        GLL(pB + kk + 16 * K,   lBbase1);
        asm volatile("s_waitcnt vmcnt(0)" ::: "memory");
        __syncthreads();

        s16x8 af[4], bfr[4];
        for (int t = 0; t < 4; ++t) {
            af[t]  = *(const s16x8*)&lsA[(mw + t * 16 + l15) * 32 + quad * 8];
            bfr[t] = *(const s16x8*)&lsB[(nw + t * 16 + l15) * 32 + quad * 8];
        }
        for (int i = 0; i < 4; ++i)
            for (int j = 0; j < 4; ++j)
                acc[i][j] = __builtin_amdgcn_mfma_f32_16x16x32_bf16(af[i], bfr[j], acc[i][j], 0, 0, 0);
    }

    if (EPI == 0) {
        for (int i = 0; i < 4; ++i) {
            int row = m0 + mw + i * 16 + quad * 4;
            for (int j = 0; j < 4; ++j) {
                int col = n0 + nw + j * 16 + l15;
                float bv = bias[col];
                for (int r = 0; r < 4; ++r)
                    Cf[(size_t)(row + r) * N + col] = acc[i][j][r] + bv;
            }
        }
    } else {
        for (int i = 0; i < 4; ++i) {
            int row = m0 + mw + i * 16 + quad * 4;
            for (int j = 0; j < 4; ++j) {
                int col = n0 + nw + j * 16 + l15;
                float bv = bias[col];
                int sel = col >> 10, h = (col >> 6) & 15, hd = col & 63;
                for (int r = 0; r < 4; ++r) {
                    int rr = row + r;
                    int b = rr >> 11, s = rr & 2047;
                    short val = f2bf(acc[i][j][r] + bv);
                    if (sel == 0)      Qo[(((size_t)b * HH + h) * SS + s) * HDD + hd] = val;
                    else if (sel == 1) Ko[(((size_t)b * HH + h) * SS + s) * HDD + hd] = val;
                    else               Vo[(((size_t)b * HH + h) * HDD + hd) * SS + s] = val;
                }
            }
        }
    }
}

// ---------------- causal flash attention, 32x32 MFMA, S^T form, pipelined ----------------
// Q,K: (b,h,s,hd) bf16; V: (b,h,hd,s) bf16; O: (b,s,h*64+hd) bf16.
// grid (16, B*H), 1024 blocks (4/CU). Block = one 128-q-row tile, qb interleaved
// for load balance. K/V/mask double-buffered in LDS; GLL for tile kt+1 issued
// BEFORE computing tile kt, so the barrier's vmcnt(0) drain is ~free.
__global__ __launch_bounds__(256, 4)
void attn_kernel(const short* __restrict__ Q, const short* __restrict__ Kb,
                 const short* __restrict__ Vb, const int* __restrict__ mask,
                 short* __restrict__ O)
{
    __shared__ short lsK[2][64 * 64];   // chunk p=key*8+(s^(key&7)) holds K[kv0+key][s'*8..]
    __shared__ short lsV[2][64 * 64];   // chunk p=hd*8+(s^(hd&7))  holds V^T[hd][kv0+s'*8..]
    __shared__ float lsM[2][64];        // additive key mask

    const int tid = threadIdx.x;
    const int w   = tid >> 6, lane = tid & 63;
    const int h   = lane >> 5, q = lane & 31;     // half-wave, q-column
    const int bx = blockIdx.x, bh = blockIdx.y;
    const int qb = (bx & 1) ? (15 - (bx >> 1)) : (bx >> 1);   // interleave heavy/light
    const int b = bh >> 4;
    const size_t baseQK = (size_t)bh * SS * HDD;
    const size_t baseV  = (size_t)bh * HDD * SS;
    const int q0 = qb * 128;
    const int s_row = q0 + w * 32 + q;
    const int T = 2 * (qb + 1);                   // 64-key tiles; last 2 causal
    const float SC = 0.18033688f;                 // (1/8) * log2(e)

    // Q fragments (B-frag: n=q, k=hd=kb*16+h*8+j)
    s16x8 bq[4];
    for (int kb = 0; kb < 4; ++kb)
        bq[kb] = *(const s16x8*)(Q + baseQK + (size_t)s_row * HDD + kb * 16 + h * 8);

    // staging addresses: 2 GLL slots each for K and V
    const short* gK[2]; const short* gV[2]; int lofs[2];
    for (int i = 0; i < 2; ++i) {
        const int p = w * 128 + i * 64 + lane;
        const int kr = p >> 3, s = p & 7;
        gK[i] = Kb + baseQK + (size_t)kr * HDD + ((s ^ (kr & 7)) * 8);
        gV[i] = Vb + baseV + (size_t)kr * SS + ((s ^ (kr & 7)) * 8);
        lofs[i] = (w * 128 + i * 64) * 8;         // wave-uniform LDS chunk base (shorts)
    }
    const int* mbase = mask + b * SS;

    float lsum = 0.f;
    f32x16 oa[2] = {};                            // O^T accs (hd halves)

    // ---- preamble: stage tile 0 into buf 0 ----
    for (int i = 0; i < 2; ++i) {
        GLL(gK[i], &lsK[0][lofs[i]]);
        GLL(gV[i], &lsV[0][lofs[i]]);
    }
    if (tid < 16) {
        int4 mv = *(const int4*)(mbase + tid * 4);
        float4 f;
        f.x = mv.x ? 0.f : -1e30f; f.y = mv.y ? 0.f : -1e30f;
        f.z = mv.z ? 0.f : -1e30f; f.w = mv.w ? 0.f : -1e30f;
        *(float4*)&lsM[0][tid * 4] = f;
    }
    __syncthreads();

    auto step = [&](int kt, auto CC) {
        constexpr bool CAUS = decltype(CC)::value;
        const int cur = kt & 1, nxt = cur ^ 1;
        const int kv0 = kt * 64;

        // prefetch tile kt+1 into buf[nxt] (lands during this tile's compute)
        int4 mv;
        const bool pf = (kt + 1 < T);
        if (pf) {
            const size_t okK = (size_t)(kv0 + 64) * HDD;
            const int   okV = kv0 + 64;
            for (int i = 0; i < 2; ++i) {
                GLL(gK[i] + okK, &lsK[nxt][lofs[i]]);
                GLL(gV[i] + okV, &lsV[nxt][lofs[i]]);
            }
            if (tid < 16) mv = *(const int4*)(mbase + kv0 + 64 + tid * 4);
        }

        // ---- compute tile kt from buf[cur] ----
        for (int nt = 0; nt < 2; ++nt) {
            // S^T: rows = keys nt*32 + (reg&3)+8*(reg>>2)+4h, col = q
            f32x16 sa = {};
            const int key = nt * 32 + q;
            for (int kb = 0; kb < 4; ++kb) {
                const int cc = (kb * 2 + h) ^ (key & 7);
                s16x8 ak = *(const s16x8*)&lsK[cur][(key * 8 + cc) * 8];
                sa = __builtin_amdgcn_mfma_f32_32x32x16_bf16(ak, bq[kb], sa, 0, 0, 0);
            }
            // softmax (fixed-offset, log2 domain): v = s*SC + madd, exp2
            unsigned int pk2[4][2];
            for (int g = 0; g < 4; ++g) {
                float4 mq = *(const float4*)&lsM[cur][nt * 32 + 8 * g + 4 * h];
                float pv[4];
                for (int r = 0; r < 4; ++r) {
                    float v = sa[g * 4 + r] * SC + ((const float*)&mq)[r];
                    if (CAUS) {
                        int keyg = kv0 + nt * 32 + 8 * g + 4 * h + r;
                        if (keyg > s_row) v = -1e30f;
                    }
                    float p = __builtin_amdgcn_exp2f(v);
                    pv[r] = p;
                    lsum += p;
                }
                pk2[g][0] = permpack(pv[0], pv[1]);
                pk2[g][1] = permpack(pv[2], pv[3]);
            }
            // O^T += V^T P^T : P B-frag via half-wave exchange
            for (int kb2 = 0; kb2 < 2; ++kb2) {
                const int g_own = 2 * kb2 + h;
                unsigned int s0 = h ? pk2[2 * kb2][0] : pk2[2 * kb2 + 1][0];
                unsigned int s1 = h ? pk2[2 * kb2][1] : pk2[2 * kb2 + 1][1];
                unsigned int r0 = (unsigned int)__shfl_xor((int)s0, 32);
                unsigned int r1 = (unsigned int)__shfl_xor((int)s1, 32);
                union { s16x8 v; unsigned int d[4]; } bp;
                if (h == 0) { bp.d[0] = pk2[g_own][0]; bp.d[1] = pk2[g_own][1]; bp.d[2] = r0; bp.d[3] = r1; }
                else        { bp.d[0] = r0; bp.d[1] = r1; bp.d[2] = pk2[g_own][0]; bp.d[3] = pk2[g_own][1]; }
                for (int mt = 0; mt < 2; ++mt) {
                    const int hd = mt * 32 + q;
                    const int cc = (nt * 4 + kb2 * 2 + h) ^ (hd & 7);
                    s16x8 av = *(const s16x8*)&lsV[cur][(hd * 8 + cc) * 8];
                    oa[mt] = __builtin_amdgcn_mfma_f32_32x32x16_bf16(av, bp.v, oa[mt], 0, 0, 0);
                }
            }
        }

        if (pf && tid < 16) {
            float4 f;
            f.x = mv.x ? 0.f : -1e30f; f.y = mv.y ? 0.f : -1e30f;
            f.z = mv.z ? 0.f : -1e30f; f.w = mv.w ? 0.f : -1e30f;
            *(float4*)&lsM[nxt][tid * 4] = f;
        }
        __syncthreads();   // vmcnt(0) drain ~free: GLLs issued a whole tile ago
    };

    int kt = 0;
    for (; kt < T - 2; ++kt) step(kt, std::false_type{});
    step(kt, std::true_type{}); ++kt;
    step(kt, std::true_type{});

    // epilogue: normalize, O^T regs -> O (b, s, head*64+hd) bf16
    float ls2 = lsum + __shfl_xor(lsum, 32);
    float inv = 1.0f / ls2;
    const int hcol = (bh & 15) * HDD;
    const size_t obase = ((size_t)b * SS + s_row) * DD + hcol;
    for (int mt = 0; mt < 2; ++mt) {
        for (int g = 0; g < 4; ++g) {
            const int hd0 = mt * 32 + 8 * g + 4 * h;
            uint2 st;
            st.x = permpack(oa[mt][g * 4 + 0] * inv, oa[mt][g * 4 + 1] * inv);
            st.y = permpack(oa[mt][g * 4 + 2] * inv, oa[mt][g * 4 + 3] * inv);
            *(uint2*)&O[obase + hd0] = st;
        }
    }
}

// ---------------- launch ----------------
extern "C" void kernel_launch(void* const* d_in, const int* in_sizes, int n_in,
                              void* d_out, int out_size, void* d_ws, size_t ws_size,
                              hipStream_t stream) {
    const float* x     = (const float*)d_in[0];
    const int*   mask  = (const int*)d_in[1];
    const float* qkv_w = (const float*)d_in[2];
    const float* qkv_b = (const float*)d_in[3];
    const float* out_w = (const float*)d_in[4];
    const float* out_b = (const float*)d_in[5];
    float* out = (float*)d_out;

    const size_t M1 = (size_t)BB * SS;       // 8192
    short* ws  = (short*)d_ws;
    short* xb  = ws;
    short* qwb = xb  + M1 * DD;
    short* owb = qwb + (size_t)3 * DD * DD;
    short* Qb  = owb + (size_t)DD * DD;
    short* Kb  = Qb  + M1 * DD;
    short* Vb  = Kb  + M1 * DD;
    short* Ob  = Vb  + M1 * DD;

    cvt_kernel<<<(int)(M1 * DD / 8 / 256), 256, 0, stream>>>(x, xb, (int)(M1 * DD));
    cvt_kernel<<<3 * DD * DD / 8 / 256, 256, 0, stream>>>(qkv_w, qwb, 3 * DD * DD);
    cvt_kernel<<<DD * DD / 8 / 256, 256, 0, stream>>>(out_w, owb, DD * DD);

    gemm_bt<1><<<dim3(64, 24), 256, 0, stream>>>(xb, qwb, qkv_b, nullptr,
                                                 Qb, Kb, Vb, 8192, 3072, 1024);
    attn_kernel<<<dim3(16, BB * HH), 256, 0, stream>>>(Qb, Kb, Vb, mask, Ob);
    gemm_bt<0><<<dim3(64, 8), 256, 0, stream>>>(Ob, owb, out_b, out,
                                                nullptr, nullptr, nullptr, 8192, 1024, 1024);
}